// Round 4
// baseline (153.823 us; speedup 1.0000x reference)
//
#include <hip/hip_runtime.h>

// DeformableConv2D round 8: phase B with ZERO LDS traffic in the tap loop.
//
// Rounds 5-7 post-mortem: VALUBusy pinned at ~24% across occupancy 23->49%
// and across gather-ILP restructures => a fixed-throughput pipe saturates.
// Count per block (old phase B): 1152 uniform ds_read_b128 (cw/ci broadcasts)
// + 576 ds_write_b16 + 72 A-frag ds_read_b128 ~= 16.7K LDS-pipe cycles/block,
// plus a per-tap serial chain THROUGH the LDS pipe (table read -> gather ->
// fma -> ds_write s_sa -> ds_read_b128 -> MFMA).
//
// Fix: lane remap. Phase-B lane (kq,m) handles pixel m, channels kq*8..+7 --
// exactly the MFMA A-frag layout. So:
//   * cw/ci tables read per-lane: 2 ds_read_b128 per tap per wave (was 32),
//     table stored transposed [kg][p] so the lane read is contiguous.
//   * bilinear blend produces the A-frag directly in registers: s_sa deleted,
//     no LDS writes, no stores anywhere in the tap loop.
//   * gathers become 16 x global_load_dwordx4 per tap per wave (same bytes,
//     4x fewer VMEM instructions).
// LDS pipe work drops ~15x; LDS 32.3 -> 23 KB.
//
// prep: offset weights -> f16 transposed [80][576]; conv weights -> f16.
// main: 784 blocks x 256 thr (4 waves), 16 pixels/block.
//   A : offset conv as MFMA GEMM, A-frags gathered straight from global x.
//       Waves split the 5 N-tiles (wave 3 takes tiles 3 and 4). ZERO barriers.
//   A': coord/weight table, lane = sample (576 items / 256 thr), stored [kg][p].
//   B : per tap: 2 per-lane table reads, 16 dwordx4 gathers, 16 fma4 blends,
//       2 MFMAs. Next tap's table prefetched in registers. ZERO barriers.
// Barriers per block: 2.
//
// MFMA 16x16x32 f16 layouts (verified by earlier passing runs):
//   A-frag: lane holds A[m=lane&15][k=(lane>>4)*8+j]
//   B-frag: lane holds B[k=(lane>>4)*8+j][n=lane&15]   (B stored [n][k])
//   C/D  : col(n)=lane&15, row(m)=(lane>>4)*4+reg

#define NH 56
#define NW 56
#define NC 64
#define NDG 4
#define NK 9
#define NOFF 72
#define NOFFP 80
#define NF 64
#define KTOT 576
#define HWPIX 3136
#define NPIX 12544

#define WS_OFFKT 0          // f16 [80][576]   = 92160 B
#define WS_WK    92160      // f16 [9][64][64] = 73728 B

typedef _Float16 half8   __attribute__((ext_vector_type(8)));
typedef float    floatx4 __attribute__((ext_vector_type(4)));

// ---------------- prep: weight conversion ----------------
__global__ __launch_bounds__(256)
void dcn_prep(const float* __restrict__ offk,   // [3,3,64,72] (kk,oc)
              const float* __restrict__ wk,     // [3,3,64,64] (k,f,c)
              _Float16* __restrict__ offkt,     // [80][576]   (oc,kk)
              _Float16* __restrict__ wkh)       // [9][64][64]
{
    const int i = blockIdx.x * 256 + threadIdx.x;
    if (i < NOFFP * KTOT) {
        const int oc = i / KTOT;
        const int kk = i - oc * KTOT;
        const float v = (oc < NOFF) ? offk[kk * NOFF + oc] : 0.0f;
        offkt[i] = (_Float16)v;
    }
    const int j = i - NOFFP * KTOT;
    if (j >= 0 && j < NK * NF * NC) wkh[j] = (_Float16)wk[j];
}

// ---------------- fused main ----------------
__global__ __launch_bounds__(256, 4)
void dcn_main(const float* __restrict__ x,        // [4,56,56,64]
              const _Float16* __restrict__ offkt, // [80][576]
              const float* __restrict__ offb,     // [72]
              const _Float16* __restrict__ wkh,   // [9][64][64]
              float* __restrict__ out)            // [12544][64]
{
    __shared__ float s_off[16 * NOFF];                    // 4.6 KB
    __shared__ __align__(16) float s_cww[576 * 4];        // 9.2 KB  [kg][p][4]
    __shared__ __align__(16) int   s_cwi[576 * 4];        // 9.2 KB  [kg][p][4]

    const int tid  = threadIdx.x;
    const int w    = tid >> 6;      // wave id: A = N-tile, B = group
    const int lane = tid & 63;
    const int m    = lane & 15;     // MFMA row / col index
    const int kq   = lane >> 4;     // MFMA k-quad
    const int kq8  = kq * 8;

    const int pix0 = blockIdx.x * 16;
    const int pixm = pix0 + m;
    const int bm   = pixm / HWPIX;
    const int rrm  = pixm - bm * HWPIX;
    const int ohm  = rrm / NW;
    const int owm  = rrm - ohm * NW;
    const float* xbase = x + (size_t)(bm * HWPIX + ohm * NW + owm) * NC + kq8;

    // ---- phase A: offset conv GEMM, zero barriers ----
    const int oc0 = w * 16 + m;     // 0..63
    floatx4 acc0, acc1;
    { const float bv = offb[oc0]; acc0 = (floatx4){bv, bv, bv, bv}; }
    { const float bv = (w == 3 && m < 8) ? offb[64 + m] : 0.0f;
      acc1 = (floatx4){bv, bv, bv, bv}; }

    #pragma unroll
    for (int k = 0; k < NK; ++k) {
        const int ki = k / 3, kj = k - 3 * ki;
        const int ih = ohm + ki - 1, iw = owm + kj - 1;
        const bool vld = ((unsigned)ih < NH) && ((unsigned)iw < NW);
        const float* ap = xbase + ((ki - 1) * NW + (kj - 1)) * NC;
        #pragma unroll
        for (int s = 0; s < 2; ++s) {
            float4 a0 = make_float4(0.f, 0.f, 0.f, 0.f), a1 = a0;
            if (vld) {
                a0 = *(const float4*)(ap + s * 32);
                a1 = *(const float4*)(ap + s * 32 + 4);
            }
            half8 af;
            af[0] = (_Float16)a0.x; af[1] = (_Float16)a0.y;
            af[2] = (_Float16)a0.z; af[3] = (_Float16)a0.w;
            af[4] = (_Float16)a1.x; af[5] = (_Float16)a1.y;
            af[6] = (_Float16)a1.z; af[7] = (_Float16)a1.w;
            const int kkb = k * 64 + s * 32 + kq8;
            const half8 bf0 = *(const half8*)&offkt[(size_t)oc0 * KTOT + kkb];
            acc0 = __builtin_amdgcn_mfma_f32_16x16x32_f16(af, bf0, acc0, 0, 0, 0);
            if (w == 3) {
                const half8 bf1 = *(const half8*)&offkt[(size_t)(64 + m) * KTOT + kkb];
                acc1 = __builtin_amdgcn_mfma_f32_16x16x32_f16(af, bf1, acc1, 0, 0, 0);
            }
        }
    }
    #pragma unroll
    for (int r = 0; r < 4; ++r)
        s_off[(kq * 4 + r) * NOFF + oc0] = acc0[r];
    if (w == 3 && m < 8) {
        #pragma unroll
        for (int r = 0; r < 4; ++r)
            s_off[(kq * 4 + r) * NOFF + 64 + m] = acc1[r];
    }
    __syncthreads();

    // ---- phase A': coord/weight table, lane = sample, stored [kg][p] ----
    for (int i = tid; i < 16 * 36; i += 256) {
        const int p  = i / 36;
        const int kg = i - p * 36;              // k*NDG + g
        const int k  = kg >> 2;
        const int ki = k / 3, kj = k - 3 * ki;
        const int pix = pix0 + p;
        const int b   = pix / HWPIX;
        const int rr  = pix - b * HWPIX;
        const int oh  = rr / NW, ow = rr - (rr / NW) * NW;
        const float offy = s_off[p * NOFF + kg * 2 + 0];
        const float offx = s_off[p * NOFF + kg * 2 + 1];
        float yv = fminf(fmaxf((float)(oh + ki) + offy, 0.0f), 57.0f);
        float xv = fminf(fmaxf((float)(ow + kj) + offx, 0.0f), 57.0f);
        const float y0f = floorf(yv), x0f = floorf(xv);
        const int y0 = (int)y0f, x0 = (int)x0f;
        const int y1 = min(y0 + 1, 57), x1 = min(x0 + 1, 57);
        const float ly = yv - y0f,       lx = xv - x0f;
        const float hy = (float)y1 - yv, hx = (float)x1 - xv;
        const bool vy0 = (unsigned)(y0 - 1) < NH;
        const bool vy1 = (unsigned)(y1 - 1) < NH;
        const bool vx0 = (unsigned)(x0 - 1) < NW;
        const bool vx1 = (unsigned)(x1 - 1) < NW;
        const float w00 = (vy0 && vx0) ? hy * hx : 0.0f;
        const float w01 = (vy0 && vx1) ? hy * lx : 0.0f;
        const float w10 = (vy1 && vx0) ? ly * hx : 0.0f;
        const float w11 = (vy1 && vx1) ? ly * lx : 0.0f;
        const int y0c = min(max(y0 - 1, 0), NH - 1);
        const int y1c = min(max(y1 - 1, 0), NH - 1);
        const int x0c = min(max(x0 - 1, 0), NW - 1);
        const int x1c = min(max(x1 - 1, 0), NW - 1);
        const int bb = b * HWPIX;
        const int j2 = (kg * 16 + p) * 4;       // transposed: [kg][p]
        *(float4*)&s_cww[j2] = make_float4(w00, w01, w10, w11);
        *(int4*)&s_cwi[j2]   = make_int4((bb + y0c * NW + x0c) * NC,
                                         (bb + y0c * NW + x1c) * NC,
                                         (bb + y1c * NW + x0c) * NC,
                                         (bb + y1c * NW + x1c) * NC);
    }
    __syncthreads();

    // ---- phase B: sampling + grouped conv, zero LDS writes, zero barriers ----
    // lane (kq,m): pixel m, channels {kq8..kq8+7} and {32+kq8..32+kq8+7}.
    floatx4 accB = (floatx4){0.f, 0.f, 0.f, 0.f};
    float4 cw = *(const float4*)&s_cww[((0 * 4 + w) * 16 + m) * 4];
    int4   ci = *(const int4*) &s_cwi[((0 * 4 + w) * 16 + m) * 4];
    #pragma unroll 1
    for (int k = 0; k < NK; ++k) {
        // prefetch next tap's table entry (register, hides LDS latency)
        const int kn  = (k + 1 < NK) ? k + 1 : k;
        const int tbn = ((kn * 4 + w) * 16 + m) * 4;
        const float4 cwn = *(const float4*)&s_cww[tbn];
        const int4   cin = *(const int4*) &s_cwi[tbn];

        // 16 independent dwordx4 gathers: 4 corners x {lo32,hi32} x 2 float4
        float ga[16], gb[16], gc[16], gd[16];
        *(float4*)&ga[0]  = *(const float4*)&x[ci.x + kq8];
        *(float4*)&ga[4]  = *(const float4*)&x[ci.x + kq8 + 4];
        *(float4*)&ga[8]  = *(const float4*)&x[ci.x + 32 + kq8];
        *(float4*)&ga[12] = *(const float4*)&x[ci.x + 32 + kq8 + 4];
        *(float4*)&gb[0]  = *(const float4*)&x[ci.y + kq8];
        *(float4*)&gb[4]  = *(const float4*)&x[ci.y + kq8 + 4];
        *(float4*)&gb[8]  = *(const float4*)&x[ci.y + 32 + kq8];
        *(float4*)&gb[12] = *(const float4*)&x[ci.y + 32 + kq8 + 4];
        *(float4*)&gc[0]  = *(const float4*)&x[ci.z + kq8];
        *(float4*)&gc[4]  = *(const float4*)&x[ci.z + kq8 + 4];
        *(float4*)&gc[8]  = *(const float4*)&x[ci.z + 32 + kq8];
        *(float4*)&gc[12] = *(const float4*)&x[ci.z + 32 + kq8 + 4];
        *(float4*)&gd[0]  = *(const float4*)&x[ci.w + kq8];
        *(float4*)&gd[4]  = *(const float4*)&x[ci.w + kq8 + 4];
        *(float4*)&gd[8]  = *(const float4*)&x[ci.w + 32 + kq8];
        *(float4*)&gd[12] = *(const float4*)&x[ci.w + 32 + kq8 + 4];

        half8 af0, af1;
        #pragma unroll
        for (int j = 0; j < 8; ++j) {
            float v =       cw.x * ga[j];
            v = fmaf(cw.y, gb[j], v);
            v = fmaf(cw.z, gc[j], v);
            v = fmaf(cw.w, gd[j], v);
            af0[j] = (_Float16)v;
        }
        #pragma unroll
        for (int j = 0; j < 8; ++j) {
            float v =       cw.x * ga[8 + j];
            v = fmaf(cw.y, gb[8 + j], v);
            v = fmaf(cw.z, gc[8 + j], v);
            v = fmaf(cw.w, gd[8 + j], v);
            af1[j] = (_Float16)v;
        }
        const _Float16* wp = &wkh[(size_t)(k * NF + w * 16 + m) * NC];
        const half8 bf0 = *(const half8*)&wp[kq8];
        const half8 bf1 = *(const half8*)&wp[32 + kq8];
        accB = __builtin_amdgcn_mfma_f32_16x16x32_f16(af0, bf0, accB, 0, 0, 0);
        accB = __builtin_amdgcn_mfma_f32_16x16x32_f16(af1, bf1, accB, 0, 0, 0);
        cw = cwn; ci = cin;
    }

    #pragma unroll
    for (int r = 0; r < 4; ++r)
        out[(size_t)(pix0 + kq * 4 + r) * NF + w * 16 + m] = accB[r];
}

extern "C" void kernel_launch(void* const* d_in, const int* in_sizes, int n_in,
                              void* d_out, int out_size, void* d_ws, size_t ws_size,
                              hipStream_t stream) {
    const float* xin  = (const float*)d_in[0];
    const float* offk = (const float*)d_in[1];
    const float* offb = (const float*)d_in[2];
    const float* wk   = (const float*)d_in[3];
    float* outp = (float*)d_out;

    _Float16* offkt = (_Float16*)((char*)d_ws + WS_OFFKT);
    _Float16* wkh   = (_Float16*)((char*)d_ws + WS_WK);

    dcn_prep<<<324, 256, 0, stream>>>(offk, wk, offkt, wkh);
    dcn_main<<<NPIX / 16, 256, 0, stream>>>(xin, offkt, offb, wkh, outp);
}

// Round 5
// 113.741 us; speedup vs baseline: 1.3524x; 1.3524x over previous
//
#include <hip/hip_runtime.h>

// DeformableConv2D round 9: LDS-windowed sampling (kill the L2 gather chain).
//
// r5-r8 post-mortem: VALUBusy pinned ~24% (r7) / 5.8% (r8) across occupancy
// and ILP restructures => phase B is latency-bound on scattered L2 gathers
// (200-900cy) that ~12 waves/CU cannot hide. r8 also proved lane=channel's
// coalesced 256B gathers are load-bearing (lane remap -> 1.22M conflicts,
// 16 lines/instr, 96us).
//
// Fix: offsets are tiny (std 0.24, max ~1.6). Re-tile to spatially coherent
// blocks: 14 px along one row (grid 4*56*4 = 896). Stage the 5-row x 18-col
// x 64ch f32 window (22.5 KB) in LDS, zero-filled outside the image (exactly
// reproduces reference zero-padding). BOTH phase A's A-frags and phase B's
// bilinear corners read from it: gathers become 120cy conflict-free LDS reads.
// Window XOR-swizzled (dword granule ^= (pos&7)<<2) so phase A's strided
// A-frag reads don't 16-way conflict; phase B's uniform-pos lane=channel
// reads stay 2-way-free under the XOR (it just permutes lanes->banks).
// A' emits u16 window positions when all 4 corners fit, else a sentinel;
// phase B takes a rare wave-uniform global fallback (identical r7 math).
// Blend stays f32 -> numerics identical to r7.
//
// Barriers per block: 3 (stage | phase A -> s_off | A' tables).
//
// MFMA 16x16x32 f16 layouts (verified by earlier passing runs):
//   A-frag: lane holds A[m=lane&15][k=(lane>>4)*8+j]
//   B-frag: lane holds B[k=(lane>>4)*8+j][n=lane&15]   (B stored [n][k])
//   C/D  : col(n)=lane&15, row(m)=(lane>>4)*4+reg

#define NH 56
#define NW 56
#define NC 64
#define NDG 4
#define NK 9
#define NOFF 72
#define NOFFP 80
#define NF 64
#define KTOT 576
#define HWPIX 3136
#define NPIX 12544

#define PW    14            // pixels per block (one row segment; 4 segs/row)
#define WR    5             // window rows  (oh-2 .. oh+2)
#define WC    18            // window cols  (ow0-2 .. ow0+15)
#define WPOS  (WR * WC)     // 90 positions x 64ch f32 = 23040 B
#define NBLK  (4 * NH * 4)  // 896

#define WS_OFFKT 0          // f16 [80][576]   = 92160 B
#define WS_WK    92160      // f16 [9][64][64] = 73728 B

typedef _Float16 half8   __attribute__((ext_vector_type(8)));
typedef float    floatx4 __attribute__((ext_vector_type(4)));

// ---------------- prep: weight conversion ----------------
__global__ __launch_bounds__(256)
void dcn_prep(const float* __restrict__ offk,   // [3,3,64,72] (kk,oc)
              const float* __restrict__ wk,     // [3,3,64,64] (k,f,c)
              _Float16* __restrict__ offkt,     // [80][576]   (oc,kk)
              _Float16* __restrict__ wkh)       // [9][64][64]
{
    const int i = blockIdx.x * 256 + threadIdx.x;
    if (i < NOFFP * KTOT) {
        const int oc = i / KTOT;
        const int kk = i - oc * KTOT;
        const float v = (oc < NOFF) ? offk[kk * NOFF + oc] : 0.0f;
        offkt[i] = (_Float16)v;
    }
    const int j = i - NOFFP * KTOT;
    if (j >= 0 && j < NK * NF * NC) wkh[j] = (_Float16)wk[j];
}

// window swizzle: dword index for (pos, channel c)
__device__ __forceinline__ int win_idx(int pos, int c) {
    return (pos << 6) + (c ^ ((pos & 7) << 2));
}

// ---------------- fused main ----------------
__global__ __launch_bounds__(256, 4)
void dcn_main(const float* __restrict__ x,        // [4,56,56,64]
              const _Float16* __restrict__ offkt, // [80][576]
              const float* __restrict__ offb,     // [72]
              const _Float16* __restrict__ wkh,   // [9][64][64]
              float* __restrict__ out)            // [12544][64]
{
    __shared__ __align__(16) float s_win[WPOS * NC];        // 23040 B
    __shared__ float s_off[PW * NOFF];                      // 4032 B
    __shared__ __align__(16) float s_cww[PW * 36 * 4];      // 8064 B
    __shared__ __align__(8)  unsigned s_cwl[PW * 36 * 2];   // 4032 B
    __shared__ __align__(16) _Float16 s_sa[4][16 * 72];     // 9216 B
    // total ~48.4 KB -> 3 blocks/CU

    const int tid  = threadIdx.x;
    const int w    = tid >> 6;      // wave id: A = N-tile, B = group
    const int lane = tid & 63;
    const int m    = lane & 15;     // MFMA row / col index
    const int kq   = lane >> 4;     // MFMA k-quad
    const int kq8  = kq * 8;

    // block -> (b, oh, ow0)
    const int blk = blockIdx.x;
    const int b   = blk / (NH * 4);
    const int r2  = blk - b * (NH * 4);
    const int oh  = r2 >> 2;
    const int ow0 = (r2 & 3) * PW;
    const int bb  = b * HWPIX;

    // ---- stage window: rows oh-2..oh+2, cols ow0-2..ow0+15, zero-padded ----
    for (int i = tid; i < WPOS * 16; i += 256) {
        const int pos = i >> 4;
        const int g   = i & 15;                 // 16B granule (4 channels)
        const int ry  = pos / WC;
        const int rx  = pos - ry * WC;
        const int iy  = oh + ry - 2;
        const int ix  = ow0 + rx - 2;
        float4 v = make_float4(0.f, 0.f, 0.f, 0.f);
        if ((unsigned)iy < NH && (unsigned)ix < NW)
            v = *(const float4*)&x[(size_t)((bb + iy * NW + ix) * NC) + g * 4];
        *(float4*)&s_win[win_idx(pos, g * 4)] = v;
    }
    __syncthreads();

    // ---- phase A: offset conv GEMM from window, zero extra barriers ----
    const int oc0 = w * 16 + m;     // 0..63
    floatx4 acc0, acc1;
    { const float bv = offb[oc0]; acc0 = (floatx4){bv, bv, bv, bv}; }
    { const float bv = (w == 3 && m < 8) ? offb[64 + m] : 0.0f;
      acc1 = (floatx4){bv, bv, bv, bv}; }

    #pragma unroll
    for (int k = 0; k < NK; ++k) {
        const int ki = k / 3, kj = k - 3 * ki;
        // tap position for pixel m (rows m>=PW produce garbage, stores masked)
        const int pos = (ki + 1) * WC + (m + kj + 1);
        #pragma unroll
        for (int s = 0; s < 2; ++s) {
            const int c0 = s * 32 + kq8;
            const float4 a0 = *(const float4*)&s_win[win_idx(pos, c0)];
            const float4 a1 = *(const float4*)&s_win[win_idx(pos, c0 + 4)];
            half8 af;
            af[0] = (_Float16)a0.x; af[1] = (_Float16)a0.y;
            af[2] = (_Float16)a0.z; af[3] = (_Float16)a0.w;
            af[4] = (_Float16)a1.x; af[5] = (_Float16)a1.y;
            af[6] = (_Float16)a1.z; af[7] = (_Float16)a1.w;
            const int kkb = k * 64 + s * 32 + kq8;
            const half8 bf0 = *(const half8*)&offkt[(size_t)oc0 * KTOT + kkb];
            acc0 = __builtin_amdgcn_mfma_f32_16x16x32_f16(af, bf0, acc0, 0, 0, 0);
            if (w == 3) {
                const half8 bf1 = *(const half8*)&offkt[(size_t)(64 + m) * KTOT + kkb];
                acc1 = __builtin_amdgcn_mfma_f32_16x16x32_f16(af, bf1, acc1, 0, 0, 0);
            }
        }
    }
    // D rows >= PW belong to no pixel: mask stores.
    #pragma unroll
    for (int r = 0; r < 4; ++r)
        if (kq * 4 + r < PW)
            s_off[(kq * 4 + r) * NOFF + oc0] = acc0[r];
    if (w == 3 && m < 8) {
        #pragma unroll
        for (int r = 0; r < 4; ++r)
            if (kq * 4 + r < PW)
                s_off[(kq * 4 + r) * NOFF + 64 + m] = acc1[r];
    }
    __syncthreads();

    // ---- phase A': coord/weight table, lane = sample ----
    for (int i = tid; i < PW * 36; i += 256) {
        const int p  = i / 36;
        const int kg = i - p * 36;              // k*NDG + g
        const int k  = kg >> 2;
        const int ki = k / 3, kj = k - 3 * ki;
        const int ow = ow0 + p;
        const float offy = s_off[p * NOFF + kg * 2 + 0];
        const float offx = s_off[p * NOFF + kg * 2 + 1];
        float yv = fminf(fmaxf((float)(oh + ki) + offy, 0.0f), 57.0f);
        float xv = fminf(fmaxf((float)(ow + kj) + offx, 0.0f), 57.0f);
        const float y0f = floorf(yv), x0f = floorf(xv);
        const int y0 = (int)y0f, x0 = (int)x0f;
        const int y1 = min(y0 + 1, 57), x1 = min(x0 + 1, 57);
        const float ly = yv - y0f,       lx = xv - x0f;
        const float hy = (float)y1 - yv, hx = (float)x1 - xv;
        const bool vy0 = (unsigned)(y0 - 1) < NH;
        const bool vy1 = (unsigned)(y1 - 1) < NH;
        const bool vx0 = (unsigned)(x0 - 1) < NW;
        const bool vx1 = (unsigned)(x1 - 1) < NW;
        const float w00 = (vy0 && vx0) ? hy * hx : 0.0f;
        const float w01 = (vy0 && vx1) ? hy * lx : 0.0f;
        const float w10 = (vy1 && vx0) ? ly * hx : 0.0f;
        const float w11 = (vy1 && vx1) ? ly * lx : 0.0f;
        const int y0c = min(max(y0 - 1, 0), NH - 1);
        const int y1c = min(max(y1 - 1, 0), NH - 1);
        const int x0c = min(max(x0 - 1, 0), NW - 1);
        const int x1c = min(max(x1 - 1, 0), NW - 1);
        *(float4*)&s_cww[i * 4] = make_float4(w00, w01, w10, w11);
        // window coords (clamped-corner relative to window origin)
        const int ry0 = y0c - oh + 2, ry1 = y1c - oh + 2;
        const int rx0 = x0c - ow0 + 2, rx1 = x1c - ow0 + 2;
        unsigned c0 = 0xFFFFFFFFu, c1 = 0xFFFFFFFFu;
        if ((unsigned)ry0 < WR && (unsigned)ry1 < WR &&
            (unsigned)rx0 < WC && (unsigned)rx1 < WC) {
            c0 = (unsigned)(ry0 * WC + rx0) | ((unsigned)(ry0 * WC + rx1) << 16);
            c1 = (unsigned)(ry1 * WC + rx0) | ((unsigned)(ry1 * WC + rx1) << 16);
        }
        s_cwl[i * 2 + 0] = c0;
        s_cwl[i * 2 + 1] = c1;
    }
    __syncthreads();

    // ---- phase B: sampling from window + grouped conv, zero barriers ----
    floatx4 accB = (floatx4){0.f, 0.f, 0.f, 0.f};
    _Float16* sa = &s_sa[w][0];
    #pragma unroll 1
    for (int k = 0; k < NK; ++k) {
        #pragma unroll
        for (int p = 0; p < PW; ++p) {
            const int i = p * 36 + k * 4 + w;
            const float4 cw = *(const float4*)&s_cww[i * 4];
            const unsigned c0 = s_cwl[i * 2 + 0];
            const unsigned c1 = s_cwl[i * 2 + 1];
            float v;
            if (__builtin_expect(__builtin_amdgcn_readfirstlane(c0) != 0xFFFFFFFFu, 1)) {
                // fast: 4 conflict-free LDS reads (uniform pos, lane = channel)
                const int p00 = c0 & 0xFFFF, p01 = c0 >> 16;
                const int p10 = c1 & 0xFFFF, p11 = c1 >> 16;
                const float g00 = s_win[win_idx(p00, lane)];
                const float g01 = s_win[win_idx(p01, lane)];
                const float g10 = s_win[win_idx(p10, lane)];
                const float g11 = s_win[win_idx(p11, lane)];
                v =        cw.x * g00;
                v = fmaf(cw.y, g01, v);
                v = fmaf(cw.z, g10, v);
                v = fmaf(cw.w, g11, v);
            } else {
                // rare fallback: recompute clamped global indices (r7 math)
                const int kg = k * 4 + w;
                const int ki = k / 3, kj = k - 3 * ki;
                const float offy = s_off[p * NOFF + kg * 2 + 0];
                const float offx = s_off[p * NOFF + kg * 2 + 1];
                float yv = fminf(fmaxf((float)(oh + ki) + offy, 0.0f), 57.0f);
                float xv = fminf(fmaxf((float)(ow0 + p + kj) + offx, 0.0f), 57.0f);
                const int y0 = (int)floorf(yv), x0 = (int)floorf(xv);
                const int y1 = min(y0 + 1, 57), x1 = min(x0 + 1, 57);
                const int y0c = min(max(y0 - 1, 0), NH - 1);
                const int y1c = min(max(y1 - 1, 0), NH - 1);
                const int x0c = min(max(x0 - 1, 0), NW - 1);
                const int x1c = min(max(x1 - 1, 0), NW - 1);
                const float g00 = x[(size_t)((bb + y0c * NW + x0c) * NC) + lane];
                const float g01 = x[(size_t)((bb + y0c * NW + x1c) * NC) + lane];
                const float g10 = x[(size_t)((bb + y1c * NW + x0c) * NC) + lane];
                const float g11 = x[(size_t)((bb + y1c * NW + x1c) * NC) + lane];
                v =        cw.x * g00;
                v = fmaf(cw.y, g01, v);
                v = fmaf(cw.z, g10, v);
                v = fmaf(cw.w, g11, v);
            }
            sa[p * 72 + lane] = (_Float16)v;
        }
        #pragma unroll
        for (int s = 0; s < 2; ++s) {
            const half8 af = *(const half8*)&sa[m * 72 + s * 32 + kq8];
            const half8 bf = *(const half8*)&wkh[(size_t)(k * NF + w * 16 + m) * NC +
                                                 s * 32 + kq8];
            accB = __builtin_amdgcn_mfma_f32_16x16x32_f16(af, bf, accB, 0, 0, 0);
        }
    }

    #pragma unroll
    for (int r = 0; r < 4; ++r) {
        const int row = kq * 4 + r;
        if (row < PW)
            out[(size_t)(bb + oh * NW + ow0 + row) * NF + w * 16 + m] = accB[r];
    }
}

extern "C" void kernel_launch(void* const* d_in, const int* in_sizes, int n_in,
                              void* d_out, int out_size, void* d_ws, size_t ws_size,
                              hipStream_t stream) {
    const float* xin  = (const float*)d_in[0];
    const float* offk = (const float*)d_in[1];
    const float* offb = (const float*)d_in[2];
    const float* wk   = (const float*)d_in[3];
    float* outp = (float*)d_out;

    _Float16* offkt = (_Float16*)((char*)d_ws + WS_OFFKT);
    _Float16* wkh   = (_Float16*)((char*)d_ws + WS_WK);

    dcn_prep<<<324, 256, 0, stream>>>(offk, wk, offkt, wkh);
    dcn_main<<<NBLK, 256, 0, stream>>>(xin, offkt, offb, wkh, outp);
}

// Round 6
// 94.622 us; speedup vs baseline: 1.6257x; 1.2021x over previous
//
#include <hip/hip_runtime.h>

// DeformableConv2D round 10: phase B builds A-frags DIRECTLY from the LDS
// window -- no s_sa transpose round-trip.
//
// r9 post-mortem: window removed L2 gathers (FETCH halved, VALUBusy 24->32)
// but time flat at 58us: phase B still pushes ~3550 LDS ops/block through the
// pipe (table + 4x b32 gather + b16 s_sa write per px*tap, b128 re-reads) with
// a serial ds_write->ds_read hop per tap; conflicts rose to 801K (144B-stride
// s_sa reads). With the window IN LDS, the lane=channel->s_sa transpose (which
// existed for global coalescing) is pure overhead.
//
// This round: lane (kq,m) = pixel m, channels kq*8..+7. Per tap each lane
// reads its 4 corners' channels from s_win (16 ds_read_b128/wave/tap), blends
// f32 in registers, packs f16 -> MFMA A-frag. s_sa deleted; LDS ops/block
// ~5x down. Tables re-laid [k*4+w][16 px-slots] so per-lane reads/writes are
// conflict-free (r8's failure was GLOBAL coalescing + 256B-stride LDS table
// writes -- both avoided). Out-of-window lanes (|off|>~1, ~1e-4 rate) carry
// packed clamped coords (bit31 flag) -> divergent global fallback.
// Phase A upgraded: staging also writes an f16 window copy, so A-frags are
// single b128 LDS reads with zero per-tap cvt chains.
//
// LDS: s_win 23040 + s_winh 11520 + s_off 4032 + s_cww 9216 + s_cwl 4608
//    = 52416 B -> 3 blocks/CU. launch_bounds(256,3) for register headroom.
// Barriers per block: 3.
//
// MFMA 16x16x32 f16 layouts (verified by earlier passing runs):
//   A-frag: lane holds A[m=lane&15][k=(lane>>4)*8+j]
//   B-frag: lane holds B[k=(lane>>4)*8+j][n=lane&15]   (B stored [n][k])
//   C/D  : col(n)=lane&15, row(m)=(lane>>4)*4+reg

#define NH 56
#define NW 56
#define NC 64
#define NDG 4
#define NK 9
#define NOFF 72
#define NOFFP 80
#define NF 64
#define KTOT 576
#define HWPIX 3136
#define NPIX 12544

#define PW    14            // pixels per block (one row segment; 4 segs/row)
#define WR    5             // window rows  (oh-2 .. oh+2)
#define WC    18            // window cols  (ow0-2 .. ow0+15)
#define WPOS  (WR * WC)     // 90 positions
#define NBLK  (4 * NH * 4)  // 896

#define WS_OFFKT 0          // f16 [80][576]   = 92160 B
#define WS_WK    92160      // f16 [9][64][64] = 73728 B

typedef _Float16 half8   __attribute__((ext_vector_type(8)));
typedef _Float16 half4   __attribute__((ext_vector_type(4)));
typedef float    floatx4 __attribute__((ext_vector_type(4)));

// ---------------- prep: weight conversion ----------------
__global__ __launch_bounds__(256)
void dcn_prep(const float* __restrict__ offk,   // [3,3,64,72] (kk,oc)
              const float* __restrict__ wk,     // [3,3,64,64] (k,f,c)
              _Float16* __restrict__ offkt,     // [80][576]   (oc,kk)
              _Float16* __restrict__ wkh)       // [9][64][64]
{
    const int i = blockIdx.x * 256 + threadIdx.x;
    if (i < NOFFP * KTOT) {
        const int oc = i / KTOT;
        const int kk = i - oc * KTOT;
        const float v = (oc < NOFF) ? offk[kk * NOFF + oc] : 0.0f;
        offkt[i] = (_Float16)v;
    }
    const int j = i - NOFFP * KTOT;
    if (j >= 0 && j < NK * NF * NC) wkh[j] = (_Float16)wk[j];
}

// window swizzles (keep 16B granules contiguous; spread banks across pos)
__device__ __forceinline__ int win_idx(int pos, int c) {      // f32, dword units
    return (pos << 6) + (c ^ ((pos & 7) << 2));
}
__device__ __forceinline__ int winh_idx(int pos, int c) {     // f16, elem units
    return (pos << 6) + (c ^ ((pos & 7) << 3));
}

// ---------------- fused main ----------------
__global__ __launch_bounds__(256, 3)
void dcn_main(const float* __restrict__ x,        // [4,56,56,64]
              const _Float16* __restrict__ offkt, // [80][576]
              const float* __restrict__ offb,     // [72]
              const _Float16* __restrict__ wkh,   // [9][64][64]
              float* __restrict__ out)            // [12544][64]
{
    __shared__ __align__(16) float    s_win[WPOS * NC];     // 23040 B
    __shared__ __align__(16) _Float16 s_winh[WPOS * NC];    // 11520 B
    __shared__ float s_off[PW * NOFF];                      // 4032 B
    __shared__ __align__(16) float s_cww[36 * 16 * 4];      // 9216 B  [k*4+w][p]
    __shared__ __align__(8)  unsigned s_cwl[36 * 16 * 2];   // 4608 B  [k*4+w][p]

    const int tid  = threadIdx.x;
    const int w    = tid >> 6;      // wave id: A = N-tile, B = group
    const int lane = tid & 63;
    const int m    = lane & 15;     // MFMA row / col index
    const int kq   = lane >> 4;     // MFMA k-quad
    const int kq8  = kq * 8;

    // block -> (b, oh, ow0)
    const int blk = blockIdx.x;
    const int b   = blk / (NH * 4);
    const int r2  = blk - b * (NH * 4);
    const int oh  = r2 >> 2;
    const int ow0 = (r2 & 3) * PW;
    const int bb  = b * HWPIX;

    // ---- stage window (f32 + f16 copies), zero-padded outside image ----
    for (int i = tid; i < WPOS * 16; i += 256) {
        const int pos = i >> 4;
        const int g4  = (i & 15) * 4;
        const int ry  = pos / WC;
        const int rx  = pos - ry * WC;
        const int iy  = oh + ry - 2;
        const int ix  = ow0 + rx - 2;
        float4 v = make_float4(0.f, 0.f, 0.f, 0.f);
        if ((unsigned)iy < NH && (unsigned)ix < NW)
            v = *(const float4*)&x[(size_t)((bb + iy * NW + ix) * NC) + g4];
        *(float4*)&s_win[win_idx(pos, g4)] = v;
        half4 h;
        h[0] = (_Float16)v.x; h[1] = (_Float16)v.y;
        h[2] = (_Float16)v.z; h[3] = (_Float16)v.w;
        *(half4*)&s_winh[winh_idx(pos, g4)] = h;
    }
    __syncthreads();

    // ---- phase A: offset conv GEMM from f16 window, zero cvt chains ----
    const int oc0 = w * 16 + m;     // 0..63
    floatx4 acc0, acc1;
    { const float bv = offb[oc0]; acc0 = (floatx4){bv, bv, bv, bv}; }
    { const float bv = (w == 3 && m < 8) ? offb[64 + m] : 0.0f;
      acc1 = (floatx4){bv, bv, bv, bv}; }

    #pragma unroll
    for (int k = 0; k < NK; ++k) {
        const int ki = k / 3, kj = k - 3 * ki;
        const int pos = (ki + 1) * WC + (m + kj + 1);   // m>=PW: garbage, masked
        #pragma unroll
        for (int s = 0; s < 2; ++s) {
            const half8 af = *(const half8*)&s_winh[winh_idx(pos, s * 32 + kq8)];
            const int kkb = k * 64 + s * 32 + kq8;
            const half8 bf0 = *(const half8*)&offkt[(size_t)oc0 * KTOT + kkb];
            acc0 = __builtin_amdgcn_mfma_f32_16x16x32_f16(af, bf0, acc0, 0, 0, 0);
            if (w == 3) {
                const half8 bf1 = *(const half8*)&offkt[(size_t)(64 + m) * KTOT + kkb];
                acc1 = __builtin_amdgcn_mfma_f32_16x16x32_f16(af, bf1, acc1, 0, 0, 0);
            }
        }
    }
    #pragma unroll
    for (int r = 0; r < 4; ++r)
        if (kq * 4 + r < PW)
            s_off[(kq * 4 + r) * NOFF + oc0] = acc0[r];
    if (w == 3 && m < 8) {
        #pragma unroll
        for (int r = 0; r < 4; ++r)
            if (kq * 4 + r < PW)
                s_off[(kq * 4 + r) * NOFF + 64 + m] = acc1[r];
    }
    __syncthreads();

    // ---- phase A': coord/weight table, slot = (k*4+g)*16 + p ----
    for (int i = tid; i < 36 * 16; i += 256) {
        const int kg = i >> 4;                  // k*NDG + g
        const int p  = i & 15;
        float4 wv = make_float4(0.f, 0.f, 0.f, 0.f);
        unsigned c0 = 0, c1 = 0;                // pad slots: pos 0, weight 0
        if (p < PW) {
            const int k  = kg >> 2;
            const int ki = k / 3, kj = k - 3 * ki;
            const int ow = ow0 + p;
            const float offy = s_off[p * NOFF + kg * 2 + 0];
            const float offx = s_off[p * NOFF + kg * 2 + 1];
            float yv = fminf(fmaxf((float)(oh + ki) + offy, 0.0f), 57.0f);
            float xv = fminf(fmaxf((float)(ow + kj) + offx, 0.0f), 57.0f);
            const float y0f = floorf(yv), x0f = floorf(xv);
            const int y0 = (int)y0f, x0 = (int)x0f;
            const int y1 = min(y0 + 1, 57), x1 = min(x0 + 1, 57);
            const float ly = yv - y0f,       lx = xv - x0f;
            const float hy = (float)y1 - yv, hx = (float)x1 - xv;
            const bool vy0 = (unsigned)(y0 - 1) < NH;
            const bool vy1 = (unsigned)(y1 - 1) < NH;
            const bool vx0 = (unsigned)(x0 - 1) < NW;
            const bool vx1 = (unsigned)(x1 - 1) < NW;
            wv = make_float4((vy0 && vx0) ? hy * hx : 0.0f,
                             (vy0 && vx1) ? hy * lx : 0.0f,
                             (vy1 && vx0) ? ly * hx : 0.0f,
                             (vy1 && vx1) ? ly * lx : 0.0f);
            const int y0c = min(max(y0 - 1, 0), NH - 1);
            const int y1c = min(max(y1 - 1, 0), NH - 1);
            const int x0c = min(max(x0 - 1, 0), NW - 1);
            const int x1c = min(max(x1 - 1, 0), NW - 1);
            const int ry0 = y0c - oh + 2, ry1 = y1c - oh + 2;
            const int rx0 = x0c - ow0 + 2, rx1 = x1c - ow0 + 2;
            if ((unsigned)ry0 < WR && (unsigned)ry1 < WR &&
                (unsigned)rx0 < WC && (unsigned)rx1 < WC) {
                c0 = (unsigned)(ry0 * WC + rx0) | ((unsigned)(ry0 * WC + rx1) << 16);
                c1 = (unsigned)(ry1 * WC + rx0) | ((unsigned)(ry1 * WC + rx1) << 16);
            } else {                            // rare: packed clamped coords
                c0 = 0x80000000u | ((unsigned)y0c << 18) | ((unsigned)x0c << 12)
                   | ((unsigned)y1c << 6) | (unsigned)x1c;
                c1 = c0;
            }
        }
        *(float4*)&s_cww[i * 4] = wv;
        s_cwl[i * 2 + 0] = c0;
        s_cwl[i * 2 + 1] = c1;
    }
    __syncthreads();

    // ---- phase B: direct A-frag build from window, zero LDS writes ----
    floatx4 accB = (floatx4){0.f, 0.f, 0.f, 0.f};
    const int tb = w * 16 + m;                  // table slot (pixel m, group w)
    float4   cw = *(const float4*)&s_cww[tb * 4];
    unsigned c0 = s_cwl[tb * 2 + 0];
    unsigned c1 = s_cwl[tb * 2 + 1];
    #pragma unroll 1
    for (int k = 0; k < NK; ++k) {
        const int tn = (k + 1 < NK ? k + 1 : k) * 64 + tb;
        const float4   cwn = *(const float4*)&s_cww[tn * 4];
        const unsigned c0n = s_cwl[tn * 2 + 0];
        const unsigned c1n = s_cwl[tn * 2 + 1];

        const _Float16* wp = &wkh[(size_t)(k * NF + w * 16 + m) * NC];
        const half8 bf0 = *(const half8*)&wp[kq8];
        const half8 bf1 = *(const half8*)&wp[32 + kq8];

        floatx4 g00a, g00b, g01a, g01b, g10a, g10b, g11a, g11b;  // s=0 half
        floatx4 h00a, h00b, h01a, h01b, h10a, h10b, h11a, h11b;  // s=1 half
        if (__builtin_expect((c0 & 0x80000000u) == 0, 1)) {
            const int p00 = c0 & 0xFFFF, p01 = c0 >> 16;
            const int p10 = c1 & 0xFFFF, p11 = c1 >> 16;
            const int ca = kq8, cb = 32 + kq8;
            g00a = *(const floatx4*)&s_win[win_idx(p00, ca)];
            g00b = *(const floatx4*)&s_win[win_idx(p00, ca + 4)];
            g01a = *(const floatx4*)&s_win[win_idx(p01, ca)];
            g01b = *(const floatx4*)&s_win[win_idx(p01, ca + 4)];
            g10a = *(const floatx4*)&s_win[win_idx(p10, ca)];
            g10b = *(const floatx4*)&s_win[win_idx(p10, ca + 4)];
            g11a = *(const floatx4*)&s_win[win_idx(p11, ca)];
            g11b = *(const floatx4*)&s_win[win_idx(p11, ca + 4)];
            h00a = *(const floatx4*)&s_win[win_idx(p00, cb)];
            h00b = *(const floatx4*)&s_win[win_idx(p00, cb + 4)];
            h01a = *(const floatx4*)&s_win[win_idx(p01, cb)];
            h01b = *(const floatx4*)&s_win[win_idx(p01, cb + 4)];
            h10a = *(const floatx4*)&s_win[win_idx(p10, cb)];
            h10b = *(const floatx4*)&s_win[win_idx(p10, cb + 4)];
            h11a = *(const floatx4*)&s_win[win_idx(p11, cb)];
            h11b = *(const floatx4*)&s_win[win_idx(p11, cb + 4)];
        } else {
            const int y0c = (c0 >> 18) & 63, x0c = (c0 >> 12) & 63;
            const int y1c = (c0 >> 6) & 63,  x1c = c0 & 63;
            const int i00 = (bb + y0c * NW + x0c) * NC;
            const int i01 = (bb + y0c * NW + x1c) * NC;
            const int i10 = (bb + y1c * NW + x0c) * NC;
            const int i11 = (bb + y1c * NW + x1c) * NC;
            const int ca = kq8, cb = 32 + kq8;
            g00a = *(const floatx4*)&x[i00 + ca];
            g00b = *(const floatx4*)&x[i00 + ca + 4];
            g01a = *(const floatx4*)&x[i01 + ca];
            g01b = *(const floatx4*)&x[i01 + ca + 4];
            g10a = *(const floatx4*)&x[i10 + ca];
            g10b = *(const floatx4*)&x[i10 + ca + 4];
            g11a = *(const floatx4*)&x[i11 + ca];
            g11b = *(const floatx4*)&x[i11 + ca + 4];
            h00a = *(const floatx4*)&x[i00 + cb];
            h00b = *(const floatx4*)&x[i00 + cb + 4];
            h01a = *(const floatx4*)&x[i01 + cb];
            h01b = *(const floatx4*)&x[i01 + cb + 4];
            h10a = *(const floatx4*)&x[i10 + cb];
            h10b = *(const floatx4*)&x[i10 + cb + 4];
            h11a = *(const floatx4*)&x[i11 + cb];
            h11b = *(const floatx4*)&x[i11 + cb + 4];
        }

        half8 af0, af1;
        #pragma unroll
        for (int j = 0; j < 4; ++j) {
            float v0 = cw.x * g00a[j];
            v0 = fmaf(cw.y, g01a[j], v0);
            v0 = fmaf(cw.z, g10a[j], v0);
            v0 = fmaf(cw.w, g11a[j], v0);
            af0[j] = (_Float16)v0;
            float v1 = cw.x * g00b[j];
            v1 = fmaf(cw.y, g01b[j], v1);
            v1 = fmaf(cw.z, g10b[j], v1);
            v1 = fmaf(cw.w, g11b[j], v1);
            af0[4 + j] = (_Float16)v1;
            float v2 = cw.x * h00a[j];
            v2 = fmaf(cw.y, h01a[j], v2);
            v2 = fmaf(cw.z, h10a[j], v2);
            v2 = fmaf(cw.w, h11a[j], v2);
            af1[j] = (_Float16)v2;
            float v3 = cw.x * h00b[j];
            v3 = fmaf(cw.y, h01b[j], v3);
            v3 = fmaf(cw.z, h10b[j], v3);
            v3 = fmaf(cw.w, h11b[j], v3);
            af1[4 + j] = (_Float16)v3;
        }
        accB = __builtin_amdgcn_mfma_f32_16x16x32_f16(af0, bf0, accB, 0, 0, 0);
        accB = __builtin_amdgcn_mfma_f32_16x16x32_f16(af1, bf1, accB, 0, 0, 0);
        cw = cwn; c0 = c0n; c1 = c1n;
    }

    #pragma unroll
    for (int r = 0; r < 4; ++r) {
        const int row = kq * 4 + r;
        if (row < PW)
            out[(size_t)(bb + oh * NW + ow0 + row) * NF + w * 16 + m] = accB[r];
    }
}

extern "C" void kernel_launch(void* const* d_in, const int* in_sizes, int n_in,
                              void* d_out, int out_size, void* d_ws, size_t ws_size,
                              hipStream_t stream) {
    const float* xin  = (const float*)d_in[0];
    const float* offk = (const float*)d_in[1];
    const float* offb = (const float*)d_in[2];
    const float* wk   = (const float*)d_in[3];
    float* outp = (float*)d_out;

    _Float16* offkt = (_Float16*)((char*)d_ws + WS_OFFKT);
    _Float16* wkh   = (_Float16*)((char*)d_ws + WS_WK);

    dcn_prep<<<324, 256, 0, stream>>>(offk, wk, offkt, wkh);
    dcn_main<<<NBLK, 256, 0, stream>>>(xin, offkt, offb, wkh, outp);
}